// Round 9
// baseline (2234.083 us; speedup 1.0000x reference)
//
#include <hip/hip_runtime.h>
#include <hip/hip_bf16.h>
#include <math.h>
#include <stdint.h>

// Problem constants
#define T_TOK 4096
#define H_DIM 2880
#define E_NUM 16
#define ALPHA 1.702f
#define EPS_RMS 1e-5f

// Producer/consumer GEMM: BM=144 (3 consumer waves x 48 rows), BN=192, BK=32.
// Wave 3 = producer: A gl_lds 3-buf depth-2; B fp32->reg (bvA/bvB, full-step
// cover) -> cvt_pk -> bf16 LDS 2-buf. Consumers: pure frag-read + 36 MFMA.
// Barrier = lgkmcnt(0)+s_barrier only; NO vmcnt(0) anywhere in the loop.
#define PADM 144
#define BK 32
#define NK (H_DIM / BK)       // 90 = 14*6 + 6
#define MAX_RT 136
#define NCT1 30
#define NCT2 15
#define G1 (MAX_RT * NCT1)    // 4080 (div 8)
#define G2 (MAX_RT * NCT2)    // 2040 (div 8)
#define ABUF 9216             // 144 rows x 64 B (x3)
#define BBUF 12288            // 192 rows x 64 B (x2)
#define BBOFF 27648           // total LDS 52224 B

typedef __attribute__((ext_vector_type(8))) short short8;
typedef __attribute__((ext_vector_type(4))) float f32x4;

__device__ __forceinline__ unsigned short f2bf(float f) {
  unsigned u = __float_as_uint(f);
  return (unsigned short)((u + 0x7fffu + ((u >> 16) & 1u)) >> 16);
}
__device__ __forceinline__ unsigned cpk(float a, float b) {
  unsigned r;
  asm("v_cvt_pk_bf16_f32 %0, %1, %2" : "=v"(r) : "v"(a), "v"(b));
  return r;
}
__device__ __forceinline__ void gl_lds16(const void* g, unsigned char* lds_dst) {
  __builtin_amdgcn_global_load_lds(
      (const __attribute__((address_space(1))) void*)g,
      (__attribute__((address_space(3))) void*)lds_dst, 16, 0, 0);
}
#define ENDSTEP() do {                                           \
    asm volatile("s_waitcnt lgkmcnt(0)" ::: "memory");           \
    __builtin_amdgcn_s_barrier();                                \
    __builtin_amdgcn_sched_barrier(0);                           \
  } while (0)

// ---------------- K1: rmsnorm + fp32 gate + top4 ----------------
__global__ __launch_bounds__(256) void k_norm_gate(
    const float* __restrict__ x, const float* __restrict__ norm_w,
    const float* __restrict__ gate_w, const float* __restrict__ gate_b,
    unsigned short* __restrict__ t_out,
    int* __restrict__ topk_id, float* __restrict__ topk_w,
    int* __restrict__ counts)
{
  int t = blockIdx.x, tid = threadIdx.x;
  const float4* xr = (const float4*)(x + (size_t)t * H_DIM);
  float4 xa[3];
  float ss = 0.f;
  int j = 0;
  for (int i = tid; i < 720; i += 256, j++) {
    float4 v = xr[i]; xa[j] = v;
    ss += v.x * v.x + v.y * v.y + v.z * v.z + v.w * v.w;
  }
#pragma unroll
  for (int o = 1; o < 64; o <<= 1) ss += __shfl_xor(ss, o, 64);
  __shared__ float red[4];
  if ((tid & 63) == 0) red[tid >> 6] = ss;
  __syncthreads();
  float rs = rsqrtf((red[0] + red[1] + red[2] + red[3]) * (1.f / H_DIM) + EPS_RMS);

  float part[16];
#pragma unroll
  for (int q = 0; q < 16; q++) part[q] = 0.f;
  j = 0;
  for (int i = tid; i < 720; i += 256, j++) {
    float4 v = xa[j];
    float4 w = ((const float4*)norm_w)[i];
    float t0 = v.x * rs * w.x, t1 = v.y * rs * w.y;
    float t2 = v.z * rs * w.z, t3 = v.w * rs * w.w;
    ushort4 b; b.x = f2bf(t0); b.y = f2bf(t1); b.z = f2bf(t2); b.w = f2bf(t3);
    ((ushort4*)(t_out + (size_t)t * H_DIM))[i] = b;
#pragma unroll
    for (int q = 0; q < 16; q++) {
      float4 g = ((const float4*)(gate_w + (size_t)q * H_DIM))[i];
      part[q] += t0 * g.x + t1 * g.y + t2 * g.z + t3 * g.w;
    }
  }
  __shared__ float lg[4][16];
#pragma unroll
  for (int q = 0; q < 16; q++) {
    float p = part[q];
#pragma unroll
    for (int o = 1; o < 64; o <<= 1) p += __shfl_xor(p, o, 64);
    if ((tid & 63) == 0) lg[tid >> 6][q] = p;
  }
  __syncthreads();
  if (tid == 0) {
    float logit[16];
    for (int q = 0; q < 16; q++)
      logit[q] = lg[0][q] + lg[1][q] + lg[2][q] + lg[3][q] + gate_b[q];
    unsigned used = 0; int idx[4]; float val[4];
    for (int k = 0; k < 4; k++) {
      float best = -3.4e38f; int bi = 0;
      for (int q = 0; q < 16; q++)
        if (!((used >> q) & 1u) && logit[q] > best) { best = logit[q]; bi = q; }
      used |= 1u << bi; idx[k] = bi; val[k] = best;
    }
    float s0 = 0.f, w4[4];
    for (int k = 0; k < 4; k++) { w4[k] = expf(val[k] - val[0]); s0 += w4[k]; }
    for (int k = 0; k < 4; k++) {
      topk_id[t * 4 + k] = idx[k];
      topk_w[t * 4 + k] = w4[k] / s0;
      atomicAdd(&counts[idx[k]], 1);
    }
  }
}

// ---------------- K2a: padded prefix offsets ----------------
__global__ void k_offsets(const int* __restrict__ counts, int* __restrict__ d_off) {
  if (threadIdx.x == 0) {
    int acc = 0;
    for (int q = 0; q < 16; q++) {
      d_off[q] = acc;
      acc += ((counts[q] + PADM - 1) / PADM) * PADM;
    }
    d_off[16] = acc;
  }
}

// ---------------- K2b: routing lists (token order); padding tok = -1 ----------------
__global__ __launch_bounds__(256) void k_fill(
    const int* __restrict__ topk_id, const float* __restrict__ topk_w,
    const int* __restrict__ counts, const int* __restrict__ d_off,
    int* __restrict__ perm_tok, float* __restrict__ perm_w,
    int* __restrict__ perm_sl)
{
  int e = blockIdx.x;
  int base = d_off[e], pe = d_off[e + 1] - base, cnt = counts[e];
  int tid = threadIdx.x, lane = tid & 63, wv = tid >> 6;
  __shared__ int wsum[4];
  int pos = 0;
  for (int c0 = 0; c0 < T_TOK; c0 += 256) {
    int tok = c0 + tid;
    int4 ids = ((const int4*)topk_id)[tok];
    int flag = 0, slot = 0;
    if (ids.x == e) { flag = 1; slot = 0; }
    else if (ids.y == e) { flag = 1; slot = 1; }
    else if (ids.z == e) { flag = 1; slot = 2; }
    else if (ids.w == e) { flag = 1; slot = 3; }
    unsigned long long b = __ballot(flag);
    int wprefix = __popcll(b & ((1ULL << lane) - 1ULL));
    if (lane == 0) wsum[wv] = __popcll(b);
    __syncthreads();
    int woff = 0;
    for (int i = 0; i < wv; i++) woff += wsum[i];
    int tot = wsum[0] + wsum[1] + wsum[2] + wsum[3];
    if (flag) {
      int p = base + pos + woff + wprefix;
      perm_tok[p] = tok;
      perm_w[p] = topk_w[tok * 4 + slot];
      perm_sl[p] = slot;
    }
    pos += tot;
    __syncthreads();
  }
  for (int i = cnt + tid; i < pe; i += 256) {
    perm_tok[base + i] = -1;
    perm_w[base + i] = 0.f;
    perm_sl[base + i] = 0;
  }
}

// ---- producer macros ----
#define P_STAGE_A(abuf, ktn) do {                                             \
  _Pragma("unroll")                                                           \
  for (int i = 0; i < 9; i++)                                                 \
    gl_lds16(aptr9[i] + (size_t)(ktn) * BK,                                   \
             lds + (abuf) * ABUF + lofs + i * 1024);                          \
} while (0)

#define P_LOAD_B(set, ktn) do {                                               \
  _Pragma("unroll")                                                           \
  for (int j = 0; j < 6; j++) {                                               \
    set[j][0] = pg4[j * 11520 + (ktn) * 8 + c4 * 2];                          \
    set[j][1] = pg4[j * 11520 + (ktn) * 8 + c4 * 2 + 1];                      \
  }                                                                           \
  _Pragma("unroll")                                                           \
  for (int j = 0; j < 6; j++) {                                               \
    set[j + 6][0] = pl4[j * 11520 + (ktn) * 8 + c4 * 2];                      \
    set[j + 6][1] = pl4[j * 11520 + (ktn) * 8 + c4 * 2 + 1];                  \
  }                                                                           \
} while (0)

#define P_PACK_B(set, bbuf) do {                                              \
  _Pragma("unroll")                                                           \
  for (int j = 0; j < 12; j++) {                                              \
    uint4 p;                                                                  \
    p.x = cpk(set[j][0].x, set[j][0].y); p.y = cpk(set[j][0].z, set[j][0].w); \
    p.z = cpk(set[j][1].x, set[j][1].y); p.w = cpk(set[j][1].z, set[j][1].w); \
    *(uint4*)(lds + BBOFF + (bbuf) * BBUF + pwoff + j * 1024) = p;            \
  }                                                                           \
} while (0)

// producer step: stage A(kt+2), load B(kt+2) into LD set, pack PK set (=B(kt+1))
#define PSTEP(AS, ktn2, LD, PK, PB) do {                                      \
  P_STAGE_A(AS, ktn2);                                                        \
  P_LOAD_B(LD, ktn2);                                                         \
  __builtin_amdgcn_sched_barrier(0);                                          \
  P_PACK_B(PK, PB);                                                           \
  ENDSTEP();                                                                  \
} while (0)

// producer full schedule (NK=90): prologue + 14x6 + tail
#define PRODUCER_PIPE() do {                                                  \
  P_STAGE_A(0, 0); P_STAGE_A(1, 1);                                           \
  P_LOAD_B(bvA, 0);                                                           \
  __builtin_amdgcn_sched_barrier(0);                                          \
  P_PACK_B(bvA, 0);                                                           \
  P_LOAD_B(bvB, 1);                                                           \
  ENDSTEP();                                                                  \
  _Pragma("unroll 1")                                                         \
  for (int u = 0; u < 14; u++) {                                              \
    int kt = 6 * u;                                                           \
    PSTEP(2, kt + 2, bvA, bvB, 1);                                            \
    PSTEP(0, kt + 3, bvB, bvA, 0);                                            \
    PSTEP(1, kt + 4, bvA, bvB, 1);                                            \
    PSTEP(2, kt + 5, bvB, bvA, 0);                                            \
    PSTEP(0, kt + 6, bvA, bvB, 1);                                            \
    PSTEP(1, kt + 7, bvB, bvA, 0);                                            \
  }                                                                           \
  PSTEP(2, 86, bvA, bvB, 1);   /* kt=84 */                                    \
  PSTEP(0, 87, bvB, bvA, 0);   /* kt=85 */                                    \
  PSTEP(1, 88, bvA, bvB, 1);   /* kt=86 */                                    \
  PSTEP(2, 89, bvB, bvA, 0);   /* kt=87 */                                    \
  P_PACK_B(bvB, 1); ENDSTEP(); /* kt=88: pack B(89) */                        \
  ENDSTEP();                   /* kt=89 */                                    \
} while (0)

// ---- consumer macros ----
#define COMPUTE(ab, bb) do {                                                  \
  const unsigned char* Abase = lds + (ab) * ABUF + abase_off;                 \
  const unsigned char* Bbase = lds + BBOFF + (bb) * BBUF + bbase_off;         \
  short8 a0 = *(const short8*)(Abase);                                        \
  short8 a1 = *(const short8*)(Abase + 1024);                                 \
  short8 a2 = *(const short8*)(Abase + 2048);                                 \
  __builtin_amdgcn_s_setprio(1);                                              \
  _Pragma("unroll")                                                           \
  for (int n = 0; n < 12; n++) {                                              \
    short8 b = *(const short8*)(Bbase + n * 1024);                            \
    acc[0][n] = __builtin_amdgcn_mfma_f32_16x16x32_bf16(a0, b, acc[0][n], 0, 0, 0); \
    acc[1][n] = __builtin_amdgcn_mfma_f32_16x16x32_bf16(a1, b, acc[1][n], 0, 0, 0); \
    acc[2][n] = __builtin_amdgcn_mfma_f32_16x16x32_bf16(a2, b, acc[2][n], 0, 0, 0); \
  }                                                                           \
  __builtin_amdgcn_s_setprio(0);                                              \
} while (0)

#define CSTEP(ab, bb) do { COMPUTE(ab, bb); ENDSTEP(); } while (0)

#define CONSUMER_PIPE() do {                                                  \
  ENDSTEP();  /* matches producer prologue barrier */                         \
  _Pragma("unroll 1")                                                         \
  for (int u = 0; u < 15; u++) {                                              \
    CSTEP(0, 0); CSTEP(1, 1); CSTEP(2, 0);                                    \
    CSTEP(0, 1); CSTEP(1, 0); CSTEP(2, 1);                                    \
  }                                                                           \
} while (0)

// ================= K3: grouped gemm1 + bias + SwiGLU -> act =================
__global__ __launch_bounds__(256, 2) void k_gemm1(
    const unsigned short* __restrict__ t_bf16,
    const float* __restrict__ w1, const float* __restrict__ b1,
    const int* __restrict__ perm_tok, const int* __restrict__ d_off,
    unsigned short* __restrict__ act)
{
  __shared__ __align__(16) unsigned char lds[3 * ABUF + 2 * BBUF];  // 52224 B
  const int total = d_off[16];
  int bid = blockIdx.x;
  int wg = (bid & 7) * (G1 / 8) + (bid >> 3);   // XCD-chunked, rt fastest
  int ct = wg / MAX_RT, rt = wg % MAX_RT;
  int rowbase = rt * PADM;
  if (rowbase >= total) return;
  int e = 0;
#pragma unroll
  for (int q = 0; q < E_NUM; q++) if (d_off[q + 1] <= rowbase) e = q + 1;

  int tid = threadIdx.x, lane = tid & 63, wv = tid >> 6;

  if (wv == 3) {
    // ---------------- producer ----------------
    int r0 = lane >> 2, c4 = lane & 3;
    int acs = (lane & 3) ^ ((lane >> 3) & 3);
    unsigned lofs = (unsigned)lane * 16;
    const unsigned short* aptr9[9];
#pragma unroll
    for (int i = 0; i < 9; i++) {
      int tok = perm_tok[rowbase + r0 + 16 * i];
      if (tok < 0) tok = 0;
      aptr9[i] = t_bf16 + (size_t)tok * H_DIM + acs * 8;
    }
    size_t g0 = (size_t)e * (2 * H_DIM) + (size_t)(ct * 96) + r0;
    const float4* pg4 = (const float4*)(w1 + g0 * H_DIM);
    const float4* pl4 = (const float4*)(w1 + (g0 + H_DIM) * H_DIM);
    unsigned pwoff = (unsigned)(r0 * 64) + ((unsigned)(c4 ^ ((r0 >> 1) & 3)) << 4);
    float4 bvA[12][2], bvB[12][2];
    PRODUCER_PIPE();
  } else {
    // ---------------- consumer ----------------
    int lr = lane & 15, ch = lane >> 4;
    unsigned swz16 = (unsigned)((ch ^ ((lr >> 1) & 3)) << 4);
    unsigned abase_off = (unsigned)(wv * 3072 + lr * 64) + swz16;
    unsigned bbase_off = (unsigned)(lr * 64) + swz16;
    f32x4 zero = {0.f, 0.f, 0.f, 0.f};
    f32x4 acc[3][12];
#pragma unroll
    for (int m = 0; m < 3; m++)
#pragma unroll
      for (int n = 0; n < 12; n++) acc[m][n] = zero;

    CONSUMER_PIPE();

    int rq = lane >> 4;
#pragma unroll
    for (int m = 0; m < 3; m++) {
      int row0 = rowbase + wv * 48 + m * 16 + rq * 4;
#pragma unroll
      for (int n = 0; n < 6; n++) {
        int col = ct * 96 + n * 16 + lr;
        float bg = b1[(size_t)e * (2 * H_DIM) + col];
        float bl = b1[(size_t)e * (2 * H_DIM) + H_DIM + col];
#pragma unroll
        for (int j = 0; j < 4; j++) {
          float g = acc[m][n][j] + bg;
          float l = acc[m][n + 6][j] + bl;
          float s = 1.f / (1.f + __expf(-ALPHA * g));
          act[(size_t)(row0 + j) * H_DIM + col] = f2bf(g * s * (l + 1.f));
        }
      }
    }
  }
}

// ========== K4: grouped gemm2 + bias; weighted bf16 slot stores ==========
__global__ __launch_bounds__(256, 2) void k_gemm2(
    const unsigned short* __restrict__ act,
    const float* __restrict__ w2, const float* __restrict__ b2,
    const int* __restrict__ perm_tok, const float* __restrict__ perm_w,
    const int* __restrict__ perm_sl, const int* __restrict__ d_off,
    unsigned short* __restrict__ yslot)
{
  __shared__ __align__(16) unsigned char lds[3 * ABUF + 2 * BBUF];  // 52224 B
  const int total = d_off[16];
  int bid = blockIdx.x;
  int wg = (bid & 7) * (G2 / 8) + (bid >> 3);
  int ct = wg / MAX_RT, rt = wg % MAX_RT;
  int rowbase = rt * PADM;
  if (rowbase >= total) return;
  int e = 0;
#pragma unroll
  for (int q = 0; q < E_NUM; q++) if (d_off[q + 1] <= rowbase) e = q + 1;

  int tid = threadIdx.x, lane = tid & 63, wv = tid >> 6;

  if (wv == 3) {
    // ---------------- producer ----------------
    int r0 = lane >> 2, c4 = lane & 3;
    int acs = (lane & 3) ^ ((lane >> 3) & 3);
    unsigned lofs = (unsigned)lane * 16;
    const unsigned short* aptr9[9];
#pragma unroll
    for (int i = 0; i < 9; i++)
      aptr9[i] = act + (size_t)(rowbase + r0 + 16 * i) * H_DIM + acs * 8;
    size_t g0 = (size_t)e * H_DIM + (size_t)(ct * 192) + r0;
    const float4* pg4 = (const float4*)(w2 + g0 * H_DIM);
    const float4* pl4 = (const float4*)(w2 + (g0 + 96) * H_DIM);
    unsigned pwoff = (unsigned)(r0 * 64) + ((unsigned)(c4 ^ ((r0 >> 1) & 3)) << 4);
    float4 bvA[12][2], bvB[12][2];
    PRODUCER_PIPE();
  } else {
    // ---------------- consumer ----------------
    int lr = lane & 15, ch = lane >> 4;
    unsigned swz16 = (unsigned)((ch ^ ((lr >> 1) & 3)) << 4);
    unsigned abase_off = (unsigned)(wv * 3072 + lr * 64) + swz16;
    unsigned bbase_off = (unsigned)(lr * 64) + swz16;
    f32x4 zero = {0.f, 0.f, 0.f, 0.f};
    f32x4 acc[3][12];
#pragma unroll
    for (int m = 0; m < 3; m++)
#pragma unroll
      for (int n = 0; n < 12; n++) acc[m][n] = zero;

    CONSUMER_PIPE();

    int rq = lane >> 4;
#pragma unroll
    for (int m = 0; m < 3; m++) {
      int rl0 = wv * 48 + m * 16 + rq * 4;
#pragma unroll
      for (int j = 0; j < 4; j++) {
        int rl = rl0 + j;
        int tk = perm_tok[rowbase + rl];
        float w = perm_w[rowbase + rl];
        int sl = perm_sl[rowbase + rl];
        if (tk >= 0) {
#pragma unroll
          for (int n = 0; n < 12; n++) {
            int col = ct * 192 + n * 16 + lr;
            float y = (acc[m][n][j] + b2[(size_t)e * H_DIM + col]) * w;
            yslot[((size_t)sl * T_TOK + tk) * H_DIM + col] = f2bf(y);
          }
        }
      }
    }
  }
}

// ---------------- K5: combine — out = x + sum_k slot_k ----------------
__global__ __launch_bounds__(256) void k_comb(
    const float* __restrict__ x, const unsigned short* __restrict__ yslot,
    float* __restrict__ out)
{
  const int n8 = T_TOK * H_DIM / 8;
  int i = blockIdx.x * 256 + threadIdx.x;
  int stride = gridDim.x * 256;
  for (; i < n8; i += stride) {
    float4 x0 = ((const float4*)x)[2 * i];
    float4 x1 = ((const float4*)x)[2 * i + 1];
    float s[8] = {x0.x, x0.y, x0.z, x0.w, x1.x, x1.y, x1.z, x1.w};
#pragma unroll
    for (int k = 0; k < 4; k++) {
      uint4 v = ((const uint4*)(yslot + (size_t)k * T_TOK * H_DIM))[i];
      unsigned u[4] = {v.x, v.y, v.z, v.w};
#pragma unroll
      for (int q = 0; q < 4; q++) {
        s[2 * q]     += __uint_as_float(u[q] << 16);
        s[2 * q + 1] += __uint_as_float(u[q] & 0xffff0000u);
      }
    }
    float4 o0 = {s[0], s[1], s[2], s[3]};
    float4 o1 = {s[4], s[5], s[6], s[7]};
    ((float4*)out)[2 * i] = o0;
    ((float4*)out)[2 * i + 1] = o1;
  }
}

// ---------------- launch ----------------
extern "C" void kernel_launch(void* const* d_in, const int* in_sizes, int n_in,
                              void* d_out, int out_size, void* d_ws, size_t ws_size,
                              hipStream_t stream)
{
  const float* x      = (const float*)d_in[0];
  const float* norm_w = (const float*)d_in[1];
  const float* gate_w = (const float*)d_in[2];
  const float* gate_b = (const float*)d_in[3];
  const float* w1     = (const float*)d_in[4];
  const float* b1     = (const float*)d_in[5];
  const float* w2     = (const float*)d_in[6];
  const float* b2     = (const float*)d_in[7];
  float* out = (float*)d_out;
  char* ws = (char*)d_ws;

  // ws layout (~233.4 MB; ws_size >= 271.6 MB verified in R7)
  unsigned short* t_bf16  = (unsigned short*)(ws);                    // 23,592,960
  unsigned short* act     = (unsigned short*)(ws + 23592960);         // 115,015,680 (19584*2880*2 = 112,803,840 used)
  int*            topk_id = (int*)(ws + 138608640);
  float*          topk_w  = (float*)(ws + 138674176);
  int*            perm_tk = (int*)(ws + 138739712);                   // 78,336 used
  float*          perm_w  = (float*)(ws + 138819584);
  int*            perm_sl = (int*)(ws + 138899456);
  int*            counts  = (int*)(ws + 138979328);
  int*            d_off   = (int*)(ws + 138979392);
  unsigned short* yslot   = (unsigned short*)(ws + 138979840);        // 94,371,840

  hipMemsetAsync(counts, 0, 64, stream);
  hipLaunchKernelGGL(k_norm_gate, dim3(T_TOK), dim3(256), 0, stream,
                     x, norm_w, gate_w, gate_b, t_bf16, topk_id, topk_w, counts);
  hipLaunchKernelGGL(k_offsets, dim3(1), dim3(64), 0, stream, counts, d_off);
  hipLaunchKernelGGL(k_fill, dim3(16), dim3(256), 0, stream,
                     topk_id, topk_w, counts, d_off, perm_tk, perm_w, perm_sl);
  hipLaunchKernelGGL(k_gemm1, dim3(G1), dim3(256), 0, stream,
                     t_bf16, w1, b1, perm_tk, d_off, act);
  hipLaunchKernelGGL(k_gemm2, dim3(G2), dim3(256), 0, stream,
                     act, w2, b2, perm_tk, perm_w, perm_sl, d_off, yslot);
  hipLaunchKernelGGL(k_comb, dim3(2048), dim3(256), 0, stream, x, yslot, out);
}

// Round 10
// 1476.717 us; speedup vs baseline: 1.5129x; 1.5129x over previous
//
#include <hip/hip_runtime.h>
#include <hip/hip_bf16.h>
#include <math.h>
#include <stdint.h>

// Problem constants
#define T_TOK 4096
#define H_DIM 2880
#define E_NUM 16
#define ALPHA 1.702f
#define EPS_RMS 1e-5f

// GEMM: BM=192, BN=192 eff, BK=32; 512 threads = 8 waves (4m x 2n), wave tile
// 48 x 96. R5-proven 2-phase pipeline: A 3-buf gl_lds depth-2 (register-free),
// B 2-buf LDS with depth-1 register prefetch (<=16 VGPR/thread at 512 thr).
// Barrier = lgkmcnt(0)+s_barrier only; NO vmcnt(0) in the main loop.
#define PADM 192
#define BK 32
#define NK (H_DIM / BK)       // 90
#define MAX_RT 104
#define NCT1 30
#define NCT2 15
#define G1 (MAX_RT * NCT1)    // 3120 (div 8)
#define G2 (MAX_RT * NCT2)    // 1560 (div 8)
#define ABUF 12288            // 192 rows x 64 B (x3)
#define BBUF 12288            // 192 rows x 64 B (x2)
#define BOFF 36864            // total LDS 60 KB

typedef __attribute__((ext_vector_type(8))) short short8;
typedef __attribute__((ext_vector_type(4))) float f32x4;

__device__ __forceinline__ unsigned short f2bf(float f) {
  unsigned u = __float_as_uint(f);
  return (unsigned short)((u + 0x7fffu + ((u >> 16) & 1u)) >> 16);
}
__device__ __forceinline__ unsigned cpk(float a, float b) {
  unsigned r;
  asm("v_cvt_pk_bf16_f32 %0, %1, %2" : "=v"(r) : "v"(a), "v"(b));
  return r;
}
__device__ __forceinline__ void gl_lds16(const void* g, unsigned char* lds_dst) {
  __builtin_amdgcn_global_load_lds(
      (const __attribute__((address_space(1))) void*)g,
      (__attribute__((address_space(3))) void*)lds_dst, 16, 0, 0);
}
#define ENDSTEP() do {                                           \
    asm volatile("s_waitcnt lgkmcnt(0)" ::: "memory");           \
    __builtin_amdgcn_s_barrier();                                \
    __builtin_amdgcn_sched_barrier(0);                           \
  } while (0)

// ---------------- K1: rmsnorm + fp32 gate + top4 ----------------
__global__ __launch_bounds__(256) void k_norm_gate(
    const float* __restrict__ x, const float* __restrict__ norm_w,
    const float* __restrict__ gate_w, const float* __restrict__ gate_b,
    unsigned short* __restrict__ t_out,
    int* __restrict__ topk_id, float* __restrict__ topk_w,
    int* __restrict__ counts)
{
  int t = blockIdx.x, tid = threadIdx.x;
  const float4* xr = (const float4*)(x + (size_t)t * H_DIM);
  float4 xa[3];
  float ss = 0.f;
  int j = 0;
  for (int i = tid; i < 720; i += 256, j++) {
    float4 v = xr[i]; xa[j] = v;
    ss += v.x * v.x + v.y * v.y + v.z * v.z + v.w * v.w;
  }
#pragma unroll
  for (int o = 1; o < 64; o <<= 1) ss += __shfl_xor(ss, o, 64);
  __shared__ float red[4];
  if ((tid & 63) == 0) red[tid >> 6] = ss;
  __syncthreads();
  float rs = rsqrtf((red[0] + red[1] + red[2] + red[3]) * (1.f / H_DIM) + EPS_RMS);

  float part[16];
#pragma unroll
  for (int q = 0; q < 16; q++) part[q] = 0.f;
  j = 0;
  for (int i = tid; i < 720; i += 256, j++) {
    float4 v = xa[j];
    float4 w = ((const float4*)norm_w)[i];
    float t0 = v.x * rs * w.x, t1 = v.y * rs * w.y;
    float t2 = v.z * rs * w.z, t3 = v.w * rs * w.w;
    ushort4 b; b.x = f2bf(t0); b.y = f2bf(t1); b.z = f2bf(t2); b.w = f2bf(t3);
    ((ushort4*)(t_out + (size_t)t * H_DIM))[i] = b;
#pragma unroll
    for (int q = 0; q < 16; q++) {
      float4 g = ((const float4*)(gate_w + (size_t)q * H_DIM))[i];
      part[q] += t0 * g.x + t1 * g.y + t2 * g.z + t3 * g.w;
    }
  }
  __shared__ float lg[4][16];
#pragma unroll
  for (int q = 0; q < 16; q++) {
    float p = part[q];
#pragma unroll
    for (int o = 1; o < 64; o <<= 1) p += __shfl_xor(p, o, 64);
    if ((tid & 63) == 0) lg[tid >> 6][q] = p;
  }
  __syncthreads();
  if (tid == 0) {
    float logit[16];
    for (int q = 0; q < 16; q++)
      logit[q] = lg[0][q] + lg[1][q] + lg[2][q] + lg[3][q] + gate_b[q];
    unsigned used = 0; int idx[4]; float val[4];
    for (int k = 0; k < 4; k++) {
      float best = -3.4e38f; int bi = 0;
      for (int q = 0; q < 16; q++)
        if (!((used >> q) & 1u) && logit[q] > best) { best = logit[q]; bi = q; }
      used |= 1u << bi; idx[k] = bi; val[k] = best;
    }
    float s0 = 0.f, w4[4];
    for (int k = 0; k < 4; k++) { w4[k] = expf(val[k] - val[0]); s0 += w4[k]; }
    for (int k = 0; k < 4; k++) {
      topk_id[t * 4 + k] = idx[k];
      topk_w[t * 4 + k] = w4[k] / s0;
      atomicAdd(&counts[idx[k]], 1);
    }
  }
}

// ---------------- K2a: padded prefix offsets ----------------
__global__ void k_offsets(const int* __restrict__ counts, int* __restrict__ d_off) {
  if (threadIdx.x == 0) {
    int acc = 0;
    for (int q = 0; q < 16; q++) {
      d_off[q] = acc;
      acc += ((counts[q] + PADM - 1) / PADM) * PADM;
    }
    d_off[16] = acc;
  }
}

// ---------------- K2b: routing lists (token order); padding tok = -1 ----------------
__global__ __launch_bounds__(256) void k_fill(
    const int* __restrict__ topk_id, const float* __restrict__ topk_w,
    const int* __restrict__ counts, const int* __restrict__ d_off,
    int* __restrict__ perm_tok, float* __restrict__ perm_w,
    int* __restrict__ perm_sl)
{
  int e = blockIdx.x;
  int base = d_off[e], pe = d_off[e + 1] - base, cnt = counts[e];
  int tid = threadIdx.x, lane = tid & 63, wv = tid >> 6;
  __shared__ int wsum[4];
  int pos = 0;
  for (int c0 = 0; c0 < T_TOK; c0 += 256) {
    int tok = c0 + tid;
    int4 ids = ((const int4*)topk_id)[tok];
    int flag = 0, slot = 0;
    if (ids.x == e) { flag = 1; slot = 0; }
    else if (ids.y == e) { flag = 1; slot = 1; }
    else if (ids.z == e) { flag = 1; slot = 2; }
    else if (ids.w == e) { flag = 1; slot = 3; }
    unsigned long long b = __ballot(flag);
    int wprefix = __popcll(b & ((1ULL << lane) - 1ULL));
    if (lane == 0) wsum[wv] = __popcll(b);
    __syncthreads();
    int woff = 0;
    for (int i = 0; i < wv; i++) woff += wsum[i];
    int tot = wsum[0] + wsum[1] + wsum[2] + wsum[3];
    if (flag) {
      int p = base + pos + woff + wprefix;
      perm_tok[p] = tok;
      perm_w[p] = topk_w[tok * 4 + slot];
      perm_sl[p] = slot;
    }
    pos += tot;
    __syncthreads();
  }
  for (int i = cnt + tid; i < pe; i += 256) {
    perm_tok[base + i] = -1;
    perm_w[base + i] = 0.f;
    perm_sl[base + i] = 0;
  }
}

// ---- staging macros (512 threads; chunk tid + optional chunk 512+tid) ----
#define STAGE_A(abuf, ktn) do {                                               \
  gl_lds16(aptr0 + (size_t)(ktn) * BK, lds + (abuf) * ABUF + adst0);          \
  if (tid < 256)                                                              \
    gl_lds16(aptr1 + (size_t)(ktn) * BK, lds + (abuf) * ABUF + adst1);        \
} while (0)

#define LOAD_B(ktn) do {                                                      \
  bv[0][0] = bptr0[(ktn) * 8]; bv[0][1] = bptr0[(ktn) * 8 + 1];               \
  if (tid < 256) { bv[1][0] = bptr1[(ktn) * 8]; bv[1][1] = bptr1[(ktn) * 8 + 1]; } \
} while (0)

#define PACK_B(bbuf) do {                                                     \
  uint4 p0;                                                                   \
  p0.x = cpk(bv[0][0].x, bv[0][0].y); p0.y = cpk(bv[0][0].z, bv[0][0].w);     \
  p0.z = cpk(bv[0][1].x, bv[0][1].y); p0.w = cpk(bv[0][1].z, bv[0][1].w);     \
  *(uint4*)(lds + BOFF + (bbuf) * BBUF + bdst0) = p0;                         \
  if (tid < 256) {                                                            \
    uint4 p1;                                                                 \
    p1.x = cpk(bv[1][0].x, bv[1][0].y); p1.y = cpk(bv[1][0].z, bv[1][0].w);   \
    p1.z = cpk(bv[1][1].x, bv[1][1].y); p1.w = cpk(bv[1][1].z, bv[1][1].w);   \
    *(uint4*)(lds + BOFF + (bbuf) * BBUF + bdst1) = p1;                       \
  }                                                                           \
} while (0)

// R5-proven pipeline skeleton (COMP is the per-kernel MFMA cluster)
#define GEMM_PIPE(COMP) do {                                                  \
  STAGE_A(0, 0); STAGE_A(1, 1); LOAD_B(0);                                    \
  PACK_B(0);                                                                  \
  ENDSTEP();                                                                  \
  int ca = 0;                                                                 \
  _Pragma("unroll 1")                                                         \
  for (int u = 0; u < NK / 2; u++) {                                          \
    int kt = 2 * u;                                                           \
    int ca1 = ca + 1; if (ca1 >= 3) ca1 -= 3;                                 \
    int ca2 = ca + 2; if (ca2 >= 3) ca2 -= 3;                                 \
    if (kt + 1 < NK) LOAD_B(kt + 1);                                          \
    if (kt + 2 < NK) STAGE_A(ca2, kt + 2);                                    \
    COMP(ca, 0);                                                              \
    if (kt + 1 < NK) PACK_B(1);                                               \
    ENDSTEP();                                                                \
    if (kt + 2 < NK) LOAD_B(kt + 2);                                          \
    if (kt + 3 < NK) STAGE_A(ca, kt + 3);                                     \
    COMP(ca1, 1);                                                             \
    if (kt + 2 < NK) PACK_B(0);                                               \
    ENDSTEP();                                                                \
    ca = ca2;                                                                 \
  }                                                                           \
} while (0)

// gemm1 compute: 3 A-frags x (3 gate + 3 lin) = 18 MFMA / wave-step
#define COMP1(ab, bb) do {                                                    \
  const unsigned char* Ab = lds + (ab) * ABUF;                                \
  const unsigned char* Bb = lds + BOFF + (bb) * BBUF;                         \
  short8 a0 = *(const short8*)(Ab + abase);                                   \
  short8 a1 = *(const short8*)(Ab + abase + 1024);                            \
  short8 a2 = *(const short8*)(Ab + abase + 2048);                            \
  __builtin_amdgcn_s_setprio(1);                                              \
  _Pragma("unroll")                                                           \
  for (int n = 0; n < 3; n++) {                                               \
    short8 bg = *(const short8*)(Bb + bgbase + n * 1024);                     \
    short8 bl = *(const short8*)(Bb + blbase + n * 1024);                     \
    accg[0][n] = __builtin_amdgcn_mfma_f32_16x16x32_bf16(a0, bg, accg[0][n], 0, 0, 0); \
    accg[1][n] = __builtin_amdgcn_mfma_f32_16x16x32_bf16(a1, bg, accg[1][n], 0, 0, 0); \
    accg[2][n] = __builtin_amdgcn_mfma_f32_16x16x32_bf16(a2, bg, accg[2][n], 0, 0, 0); \
    accl[0][n] = __builtin_amdgcn_mfma_f32_16x16x32_bf16(a0, bl, accl[0][n], 0, 0, 0); \
    accl[1][n] = __builtin_amdgcn_mfma_f32_16x16x32_bf16(a1, bl, accl[1][n], 0, 0, 0); \
    accl[2][n] = __builtin_amdgcn_mfma_f32_16x16x32_bf16(a2, bl, accl[2][n], 0, 0, 0); \
  }                                                                           \
  __builtin_amdgcn_s_setprio(0);                                              \
} while (0)

// gemm2 compute: 3 A-frags x 6 B-frags = 18 MFMA / wave-step
#define COMP2(ab, bb) do {                                                    \
  const unsigned char* Ab = lds + (ab) * ABUF;                                \
  const unsigned char* Bb = lds + BOFF + (bb) * BBUF;                         \
  short8 a0 = *(const short8*)(Ab + abase);                                   \
  short8 a1 = *(const short8*)(Ab + abase + 1024);                            \
  short8 a2 = *(const short8*)(Ab + abase + 2048);                            \
  __builtin_amdgcn_s_setprio(1);                                              \
  _Pragma("unroll")                                                           \
  for (int n = 0; n < 6; n++) {                                               \
    short8 b = *(const short8*)(Bb + bbase + n * 1024);                       \
    acc[0][n] = __builtin_amdgcn_mfma_f32_16x16x32_bf16(a0, b, acc[0][n], 0, 0, 0); \
    acc[1][n] = __builtin_amdgcn_mfma_f32_16x16x32_bf16(a1, b, acc[1][n], 0, 0, 0); \
    acc[2][n] = __builtin_amdgcn_mfma_f32_16x16x32_bf16(a2, b, acc[2][n], 0, 0, 0); \
  }                                                                           \
  __builtin_amdgcn_s_setprio(0);                                              \
} while (0)

// ================= K3: grouped gemm1 + bias + SwiGLU -> act =================
__global__ __launch_bounds__(512, 4) void k_gemm1(
    const unsigned short* __restrict__ t_bf16,
    const float* __restrict__ w1, const float* __restrict__ b1,
    const int* __restrict__ perm_tok, const int* __restrict__ d_off,
    unsigned short* __restrict__ act)
{
  __shared__ __align__(16) unsigned char lds[3 * ABUF + 2 * BBUF];  // 60 KB
  const int total = d_off[16];
  int bid = blockIdx.x;
  int wg = (bid & 7) * (G1 / 8) + (bid >> 3);   // XCD-chunked, rt fastest
  int ct = wg / MAX_RT, rt = wg % MAX_RT;
  int rowbase = rt * PADM;
  if (rowbase >= total) return;
  int e = 0;
#pragma unroll
  for (int q = 0; q < E_NUM; q++) if (d_off[q + 1] <= rowbase) e = q + 1;

  int tid = threadIdx.x, lane = tid & 63, wv = tid >> 6;
  int wm = wv & 3, wn = wv >> 2;
  int lr = lane & 15, ch = lane >> 4;
  unsigned swz16 = (unsigned)((ch ^ ((lr >> 1) & 3)) << 4);
  unsigned abase  = (unsigned)((wm * 48 + lr) * 64) + swz16;   // +mf*1024
  unsigned bgbase = (unsigned)((wn * 48 + lr) * 64) + swz16;   // +nf*1024
  unsigned blbase = bgbase + 6144;                             // lin rows +96

  // A: chunks tid and 512+tid (tid<256); pre-swizzled source, linear LDS dst
  const unsigned short* aptr0; const unsigned short* aptr1 = 0;
  unsigned adst0, adst1 = 0;
  {
    int cl = tid, r = cl >> 2, c = cl & 3;
    int tok = perm_tok[rowbase + r]; if (tok < 0) tok = 0;
    aptr0 = t_bf16 + (size_t)tok * H_DIM + ((c ^ ((r >> 1) & 3)) * 8);
    adst0 = (unsigned)cl * 16;
  }
  if (tid < 256) {
    int cl = 512 + tid, r = cl >> 2, c = cl & 3;
    int tok = perm_tok[rowbase + r]; if (tok < 0) tok = 0;
    aptr1 = t_bf16 + (size_t)tok * H_DIM + ((c ^ ((r >> 1) & 3)) * 8);
    adst1 = (unsigned)cl * 16;
  }
  // B: fp32 source (linear), LDS-dst swizzled; rows 0-95 gate, 96-191 lin
  const float4* bptr0; const float4* bptr1 = 0;
  unsigned bdst0, bdst1 = 0;
  {
    int cl = tid, rr = cl >> 2, c = cl & 3;
    size_t grow = (size_t)e * (2 * H_DIM) +
                  (rr < 96 ? (size_t)(ct * 96 + rr) : (size_t)(H_DIM + ct * 96 + (rr - 96)));
    bptr0 = (const float4*)(w1 + grow * H_DIM) + c * 2;
    bdst0 = (unsigned)(rr * 64 + ((c ^ ((rr >> 1) & 3)) << 4));
  }
  if (tid < 256) {
    int cl = 512 + tid, rr = cl >> 2, c = cl & 3;
    size_t grow = (size_t)(H_DIM + ct * 96 + (rr - 96)) + (size_t)e * (2 * H_DIM);
    bptr1 = (const float4*)(w1 + grow * H_DIM) + c * 2;
    bdst1 = (unsigned)(rr * 64 + ((c ^ ((rr >> 1) & 3)) << 4));
  }

  f32x4 zero = {0.f, 0.f, 0.f, 0.f};
  f32x4 accg[3][3], accl[3][3];
#pragma unroll
  for (int m = 0; m < 3; m++)
#pragma unroll
    for (int n = 0; n < 3; n++) { accg[m][n] = zero; accl[m][n] = zero; }
  float4 bv[2][2];

  GEMM_PIPE(COMP1);

  // epilogue: bias + SwiGLU (thread-local: wave owns matching gate/lin cols)
  int rq = lane >> 4;
#pragma unroll
  for (int m = 0; m < 3; m++) {
    int row0 = rowbase + wm * 48 + m * 16 + rq * 4;
#pragma unroll
    for (int n = 0; n < 3; n++) {
      int col = ct * 96 + wn * 48 + n * 16 + lr;
      float bg = b1[(size_t)e * (2 * H_DIM) + col];
      float bl = b1[(size_t)e * (2 * H_DIM) + H_DIM + col];
#pragma unroll
      for (int j = 0; j < 4; j++) {
        float g = accg[m][n][j] + bg;
        float l = accl[m][n][j] + bl;
        float s = 1.f / (1.f + __expf(-ALPHA * g));
        act[(size_t)(row0 + j) * H_DIM + col] = f2bf(g * s * (l + 1.f));
      }
    }
  }
}

// ========== K4: grouped gemm2 + bias; weighted bf16 slot stores ==========
__global__ __launch_bounds__(512, 4) void k_gemm2(
    const unsigned short* __restrict__ act,
    const float* __restrict__ w2, const float* __restrict__ b2,
    const int* __restrict__ perm_tok, const float* __restrict__ perm_w,
    const int* __restrict__ perm_sl, const int* __restrict__ d_off,
    unsigned short* __restrict__ yslot)
{
  __shared__ __align__(16) unsigned char lds[3 * ABUF + 2 * BBUF];  // 60 KB
  __shared__ int stok[PADM]; __shared__ float swt[PADM]; __shared__ int ssl[PADM];
  const int total = d_off[16];
  int bid = blockIdx.x;
  int wg = (bid & 7) * (G2 / 8) + (bid >> 3);
  int ct = wg / MAX_RT, rt = wg % MAX_RT;
  int rowbase = rt * PADM;
  if (rowbase >= total) return;
  int e = 0;
#pragma unroll
  for (int q = 0; q < E_NUM; q++) if (d_off[q + 1] <= rowbase) e = q + 1;

  int tid = threadIdx.x, lane = tid & 63, wv = tid >> 6;
  int wm = wv & 3, wn = wv >> 2;
  int lr = lane & 15, ch = lane >> 4;
  unsigned swz16 = (unsigned)((ch ^ ((lr >> 1) & 3)) << 4);
  unsigned abase = (unsigned)((wm * 48 + lr) * 64) + swz16;
  unsigned bbase = (unsigned)((wn * 96 + lr) * 64) + swz16;

  if (tid < PADM) {
    stok[tid] = perm_tok[rowbase + tid];
    swt[tid] = perm_w[rowbase + tid];
    ssl[tid] = perm_sl[rowbase + tid];
  }

  const unsigned short* aptr0; const unsigned short* aptr1 = 0;
  unsigned adst0, adst1 = 0;
  {
    int cl = tid, r = cl >> 2, c = cl & 3;
    aptr0 = act + (size_t)(rowbase + r) * H_DIM + ((c ^ ((r >> 1) & 3)) * 8);
    adst0 = (unsigned)cl * 16;
  }
  if (tid < 256) {
    int cl = 512 + tid, r = cl >> 2, c = cl & 3;
    aptr1 = act + (size_t)(rowbase + r) * H_DIM + ((c ^ ((r >> 1) & 3)) * 8);
    adst1 = (unsigned)cl * 16;
  }
  const float4* bptr0; const float4* bptr1 = 0;
  unsigned bdst0, bdst1 = 0;
  {
    int cl = tid, rr = cl >> 2, c = cl & 3;
    size_t grow = (size_t)e * H_DIM + (size_t)(ct * 192 + rr);
    bptr0 = (const float4*)(w2 + grow * H_DIM) + c * 2;
    bdst0 = (unsigned)(rr * 64 + ((c ^ ((rr >> 1) & 3)) << 4));
  }
  if (tid < 256) {
    int cl = 512 + tid, rr = cl >> 2, c = cl & 3;
    size_t grow = (size_t)e * H_DIM + (size_t)(ct * 192 + rr);
    bptr1 = (const float4*)(w2 + grow * H_DIM) + c * 2;
    bdst1 = (unsigned)(rr * 64 + ((c ^ ((rr >> 1) & 3)) << 4));
  }

  f32x4 zero = {0.f, 0.f, 0.f, 0.f};
  f32x4 acc[3][6];
#pragma unroll
  for (int m = 0; m < 3; m++)
#pragma unroll
    for (int n = 0; n < 6; n++) acc[m][n] = zero;
  float4 bv[2][2];

  GEMM_PIPE(COMP2);

  int rq = lane >> 4;
#pragma unroll
  for (int m = 0; m < 3; m++) {
    int rl0 = wm * 48 + m * 16 + rq * 4;
#pragma unroll
    for (int n = 0; n < 6; n++) {
      int col = ct * 192 + wn * 96 + n * 16 + lr;
      float b2v = b2[(size_t)e * H_DIM + col];
#pragma unroll
      for (int j = 0; j < 4; j++) {
        int rl = rl0 + j;
        int tk = stok[rl];
        if (tk >= 0) {
          float y = (acc[m][n][j] + b2v) * swt[rl];
          yslot[((size_t)ssl[rl] * T_TOK + tk) * H_DIM + col] = f2bf(y);
        }
      }
    }
  }
}

// ---------------- K5: combine — out = x + sum_k slot_k ----------------
__global__ __launch_bounds__(256) void k_comb(
    const float* __restrict__ x, const unsigned short* __restrict__ yslot,
    float* __restrict__ out)
{
  const int n8 = T_TOK * H_DIM / 8;
  int i = blockIdx.x * 256 + threadIdx.x;
  int stride = gridDim.x * 256;
  for (; i < n8; i += stride) {
    float4 x0 = ((const float4*)x)[2 * i];
    float4 x1 = ((const float4*)x)[2 * i + 1];
    float s[8] = {x0.x, x0.y, x0.z, x0.w, x1.x, x1.y, x1.z, x1.w};
#pragma unroll
    for (int k = 0; k < 4; k++) {
      uint4 v = ((const uint4*)(yslot + (size_t)k * T_TOK * H_DIM))[i];
      unsigned u[4] = {v.x, v.y, v.z, v.w};
#pragma unroll
      for (int q = 0; q < 4; q++) {
        s[2 * q]     += __uint_as_float(u[q] << 16);
        s[2 * q + 1] += __uint_as_float(u[q] & 0xffff0000u);
      }
    }
    float4 o0 = {s[0], s[1], s[2], s[3]};
    float4 o1 = {s[4], s[5], s[6], s[7]};
    ((float4*)out)[2 * i] = o0;
    ((float4*)out)[2 * i + 1] = o1;
  }
}

// ---------------- launch ----------------
extern "C" void kernel_launch(void* const* d_in, const int* in_sizes, int n_in,
                              void* d_out, int out_size, void* d_ws, size_t ws_size,
                              hipStream_t stream)
{
  const float* x      = (const float*)d_in[0];
  const float* norm_w = (const float*)d_in[1];
  const float* gate_w = (const float*)d_in[2];
  const float* gate_b = (const float*)d_in[3];
  const float* w1     = (const float*)d_in[4];
  const float* b1     = (const float*)d_in[5];
  const float* w2     = (const float*)d_in[6];
  const float* b2     = (const float*)d_in[7];
  float* out = (float*)d_out;
  char* ws = (char*)d_ws;

  // ws layout (~233.4 MB; ws_size >= 271.6 MB verified in R7)
  unsigned short* t_bf16  = (unsigned short*)(ws);                    // 23,592,960
  unsigned short* act     = (unsigned short*)(ws + 23592960);         // 115,015,680
  int*            topk_id = (int*)(ws + 138608640);
  float*          topk_w  = (float*)(ws + 138674176);
  int*            perm_tk = (int*)(ws + 138739712);
  float*          perm_w  = (float*)(ws + 138819584);
  int*            perm_sl = (int*)(ws + 138899456);
  int*            counts  = (int*)(ws + 138979328);
  int*            d_off   = (int*)(ws + 138979392);
  unsigned short* yslot   = (unsigned short*)(ws + 138979840);        // 94,371,840

  hipMemsetAsync(counts, 0, 64, stream);
  hipLaunchKernelGGL(k_norm_gate, dim3(T_TOK), dim3(256), 0, stream,
                     x, norm_w, gate_w, gate_b, t_bf16, topk_id, topk_w, counts);
  hipLaunchKernelGGL(k_offsets, dim3(1), dim3(64), 0, stream, counts, d_off);
  hipLaunchKernelGGL(k_fill, dim3(16), dim3(256), 0, stream,
                     topk_id, topk_w, counts, d_off, perm_tk, perm_w, perm_sl);
  hipLaunchKernelGGL(k_gemm1, dim3(G1), dim3(512), 0, stream,
                     t_bf16, w1, b1, perm_tk, d_off, act);
  hipLaunchKernelGGL(k_gemm2, dim3(G2), dim3(512), 0, stream,
                     act, w2, b2, perm_tk, perm_w, perm_sl, d_off, yslot);
  hipLaunchKernelGGL(k_comb, dim3(2048), dim3(256), 0, stream, x, yslot, out);
}